// Round 7
// baseline (208.036 us; speedup 1.0000x reference)
//
#include <hip/hip_runtime.h>

// YOLO loss, MI355X. pred [256, 2704, 9, 5] fp32 (124.6 MB) -> scalar.
//
// Empirical record (total dur_us; one ~72us ws-poison fill is fixed overhead):
//   R0 187.0 : 24336 blk f4->VGPR->LDS, memset+3 kernels
//   R1 322.7 : 80B-stride regs (uncoalesced) + fence tail
//   R2 251.5 : grid-stride deep-serial (latency-bound) + fence tail
//   R3 479.9 : launch_bounds(256,8) serialized loads + fence tail
//   R4 182.9 : 512 elem/blk LDS staging, rcp sigmoid, init-in-obj, 3 dispatches  BEST
//   R5 183.8 : + global_load_lds w=16, 1024 elem/blk (neutral)
//   R6 186.3 : 2 dispatches, idempotent per-block float2 partial slots (-3)
//
// R7 = DIAGNOSTIC: exact R6 code, but yolo_noobj_kernel is dispatched TWICE.
// The kernel is idempotent (plain stores of identical values; no atomics, no
// init), so the result is bit-identical. The total-time delta vs R6 (186.3)
// measures the true noobj duration, which is invisible in rocprof's top-5
// (every dispatch under the 72us harness fill is cut):
//   noobj_dur ~= (R7_total - 186.3) - ~4us gap.
// Pre-committed reads: 235-265 -> noobj 45-75us, big win remains inside the
// kernel (round 8 ablates stage vs compute). 205-225 -> noobj 15-35us, near
// floor; revert and declare.
//
// ws layout (floats):
//  [16 + 2*blk], [16 + 2*blk + 1] : per-block {coor, conf} partial sums

#define GHW     52
#define GCELLS  2704          // 52*52
#define NA      9
#define BATCH   256
#define NBLK    (GCELLS * NA) // 24336 elements/sample; NBLK*BATCH = 6,230,016
#define INV52   (1.0f / 52.0f)

#define ELEMS_B 1024                      // elements per block
#define NB2     6084                      // 6,230,016 / 1024 exactly
#define Q4_B    1280                      // float4s per block = 1024*5/4

typedef const __attribute__((address_space(1))) uint32_t glds_g;
typedef __attribute__((address_space(3))) uint32_t glds_l;

__device__ __forceinline__ float sigmoid_exact(float x) {
    return 1.0f / (1.0f + __expf(-x));    // IEEE div; only in tiny fin kernel
}

__device__ __forceinline__ float sigmoid_fast(float x) {
    return __builtin_amdgcn_rcpf(1.0f + __expf(-x));  // ~1 ulp; absmax 0.0 R1-R6
}

__device__ __forceinline__ float waveReduceSum(float v) {
#pragma unroll
    for (int o = 32; o > 0; o >>= 1) v += __shfl_down(v, o, 64);
    return v;
}

// ---------------- Kernel B: noobj reduction (124.6 MB pass) -----------------
// Idempotent: every run writes the same per-block partials. Safe to dispatch
// twice for timing diagnosis.
__global__ __launch_bounds__(256) void yolo_noobj_kernel(
        const float* __restrict__ pred,
        const float* __restrict__ anchors,
        float* __restrict__ ws) {
    __shared__ float4 sh4[Q4_B];        // 20KB -> 8 blocks/CU, 32 waves
    __shared__ float anch[18];
    __shared__ float red[2][4];
    int t = threadIdx.x;

    const float4* __restrict__ g4 = (const float4*)pred;
    size_t f0 = (size_t)blockIdx.x * Q4_B;
    int wbase = t & ~63;                // wave*64, wave-uniform

#pragma unroll
    for (int i = 0; i < 5; ++i) {
        __builtin_amdgcn_global_load_lds(
            (glds_g*)(g4 + f0 + i * 256 + t),
            (glds_l*)(sh4 + i * 256 + wbase),
            16, 0, 0);
    }
    if (t < 18) anch[t] = anchors[t];
    __syncthreads();                    // vmcnt(0) drain

    const float* sh = (const float*)sh4;
    unsigned e0 = (unsigned)blockIdx.x * ELEMS_B + (unsigned)t;
    unsigned a  = e0 % 9u;              // one magic-div per thread
    float accXY = 0.0f, accWH = 0.0f, confAcc = 0.0f;
#pragma unroll
    for (int h = 0; h < 4; ++h) {
        int le = t + h * 256;                       // local element 0..1023
        float aw = anch[2 * a], ah = anch[2 * a + 1];

        const float* m = sh + 5 * le;               // stride-5: 2-way (free)
        float v0 = m[0], v1 = m[1], v2 = m[2], v3 = m[3], v4 = m[4];

        float s0 = sigmoid_fast(v0);
        float s1 = sigmoid_fast(v1);
        float s4 = sigmoid_fast(v4);
        float t0 = s0 - 0.5f;                       // scale by 1/52 deferred
        float t1 = s1 - 0.5f;
        float t2 = aw * (__expf(v2) - 1.0f);        // == pred_w - anchor_w
        float t3 = ah * (__expf(v3) - 1.0f);

        accXY  += t0 * t0 + t1 * t1;
        accWH  += t2 * t2 + t3 * t3;
        confAcc += s4 * s4;

        a += 4u;                                    // (+256) mod 9 == +4
        if (a >= 9u) a -= 9u;
    }
    float coorAcc = accXY * (INV52 * INV52) + accWH;

    float rc = waveReduceSum(coorAcc);
    float rf = waveReduceSum(confAcc);
    int lane = t & 63, wid = t >> 6;
    if (lane == 0) { red[0][wid] = rc; red[1][wid] = rf; }
    __syncthreads();
    if (t == 0) {
        float cs = red[0][0] + red[0][1] + red[0][2] + red[0][3];
        float fs = red[1][0] + red[1][1] + red[1][2] + red[1][3];
        ((float2*)(ws + 16))[blockIdx.x] = make_float2(cs, fs);
    }
}

// ---------------- Kernel C: obj path + partial reduce + final combine -------
__global__ __launch_bounds__(256) void yolo_fin_kernel(
        const float* __restrict__ pred,
        const float* __restrict__ label,
        const float* __restrict__ anchors,
        const float* __restrict__ ws,
        float* __restrict__ out) {
    __shared__ float anch[18];
    __shared__ float red[4][4];
    __shared__ float objs[4];
    int t = threadIdx.x;
    if (t < 18) anch[t] = anchors[t];
    __syncthreads();

    // ---- obj path: thread t = sample t ----
    float4 lab = ((const float4*)label)[t];
    float lx = lab.x, ly = lab.y, lw = lab.z, lh = lab.w;

    int ix = (int)floorf(lx * 52.0f);
    int iy = (int)floorf(ly * 52.0f);
    int idx = ix * GHW + iy;

    // argmax over anchors of squared distance (first-max, strict >)
    int am = 0; float best = -1.0f;
#pragma unroll
    for (int a = 0; a < NA; ++a) {
        float dw = lw - anch[2 * a];
        float dh = lh - anch[2 * a + 1];
        float d = dw * dw + dh * dh;
        if (d > best) { best = d; am = a; }
    }

    const float* p = pred + (((size_t)t * GCELLS + idx) * NA + am) * 5;
    float v0 = p[0], v1 = p[1], v2 = p[2], v3 = p[3], v4 = p[4];

    float aw = anch[2 * am], ah = anch[2 * am + 1];
    float px = (sigmoid_exact(v0) + (float)ix) * INV52;
    float py = (sigmoid_exact(v1) + (float)iy) * INV52;
    float pw = aw * __expf(v2);
    float ph = ah * __expf(v3);
    float pc = sigmoid_exact(v4);

    float agx = ((float)ix + 0.5f) * INV52;
    float agy = ((float)iy + 0.5f) * INV52;

    float d0 = px - agx, d1 = py - agy, d2 = pw - aw, d3 = ph - ah;
    float coor_sq_obj = d0 * d0 + d1 * d1 + d2 * d2 + d3 * d3;
    float conf_sq_obj = pc * pc;

    float e0 = px - lx, e1 = py - ly, e2 = pw - lw, e3 = ph - lh;
    float coor_obj = e0 * e0 + e1 * e1 + e2 * e2 + e3 * e3;

    // IoU (faithful: areas = x2*y2, not (x2-x1)*(y2-y1))
    float lx1 = fmaxf(lx - lw * 0.5f, 0.0f), ly1 = fmaxf(ly - lh * 0.5f, 0.0f);
    float lx2 = fminf(lx + lw * 0.5f, 1.0f), ly2 = fminf(ly + lh * 0.5f, 1.0f);
    float qx1 = fmaxf(px - pw * 0.5f, 0.0f), qy1 = fmaxf(py - ph * 0.5f, 0.0f);
    float qx2 = fminf(px + pw * 0.5f, 1.0f), qy2 = fminf(py + ph * 0.5f, 1.0f);
    float ix1 = fmaxf(lx1, qx1), iy1 = fmaxf(ly1, qy1);
    float ix2 = fminf(lx2, qx2), iy2 = fminf(ly2, qy2);
    float la = lx2 * ly2, pa = qx2 * qy2;
    float inter = fmaxf(ix2 - ix1, 0.0f) * fmaxf(iy2 - iy1, 0.0f);
    float iou = inter / (la + pa - inter);
    float dcf = pc - iou;
    float conf_obj = dcf * dcf;

    {
        float r0 = waveReduceSum(coor_sq_obj);
        float r1 = waveReduceSum(conf_sq_obj);
        float r2 = waveReduceSum(coor_obj);
        float r3 = waveReduceSum(conf_obj);
        int lane = t & 63, wid = t >> 6;
        if (lane == 0) {
            red[0][wid] = r0; red[1][wid] = r1; red[2][wid] = r2; red[3][wid] = r3;
        }
        __syncthreads();
        if (t < 4) {
            objs[t] = red[t][0] + red[t][1] + red[t][2] + red[t][3];
        }
        __syncthreads();
    }

    // ---- noobj partial reduce: 6084 float2 slots (48KB, L2-hot) ----
    const float2* __restrict__ part = (const float2*)(ws + 16);
    float cAcc = 0.0f, fAcc = 0.0f;
    for (int k = t; k < NB2; k += 256) {
        float2 pr = part[k];
        cAcc += pr.x;
        fAcc += pr.y;
    }
    float rc = waveReduceSum(cAcc);
    float rf = waveReduceSum(fAcc);
    int lane = t & 63, wid = t >> 6;
    if (lane == 0) { red[0][wid] = rc; red[1][wid] = rf; }
    __syncthreads();
    if (t == 0) {
        float coor_all = red[0][0] + red[0][1] + red[0][2] + red[0][3];
        float conf_all = red[1][0] + red[1][1] + red[1][2] + red[1][3];
        float coor_l_noobj = (coor_all - objs[0]) / (float)(BATCH * (NBLK - 1) * 4);
        float conf_l_noobj = (conf_all - objs[1]) / (float)(BATCH * (NBLK - 1));
        float coor_l_obj = objs[2] / (float)(BATCH * 4);
        float conf_l_obj = objs[3] / (float)BATCH;
        out[0] = coor_l_obj + coor_l_noobj + conf_l_obj + conf_l_noobj;
    }
}

extern "C" void kernel_launch(void* const* d_in, const int* in_sizes, int n_in,
                              void* d_out, int out_size, void* d_ws, size_t ws_size,
                              hipStream_t stream) {
    const float* pred    = (const float*)d_in[0];
    const float* label   = (const float*)d_in[1];
    const float* anchors = (const float*)d_in[2];
    float* out = (float*)d_out;
    float* ws  = (float*)d_ws;

    // DIAGNOSTIC: noobj dispatched twice (idempotent). Delta vs R6's 186.3us
    // isolates the true noobj duration hidden below the 72us fill rows.
    yolo_noobj_kernel<<<NB2, 256, 0, stream>>>(pred, anchors, ws);
    yolo_noobj_kernel<<<NB2, 256, 0, stream>>>(pred, anchors, ws);
    yolo_fin_kernel<<<1, 256, 0, stream>>>(pred, label, anchors, ws, out);
}

// Round 8
// 184.915 us; speedup vs baseline: 1.1250x; 1.1250x over previous
//
#include <hip/hip_runtime.h>

// YOLO loss, MI355X. pred [256, 2704, 9, 5] fp32 (124.6 MB) -> scalar.
//
// Empirical record (total dur_us; one ~72us ws-poison fill is fixed overhead):
//   R0 187.0 : 24336 blk f4->VGPR->LDS, memset+3 kernels
//   R4 182.9 : 512 elem/blk LDS staging, rcp sigmoid, 3 dispatches   BEST
//   R5 183.8 : + global_load_lds w=16, 1024 elem/blk (neutral)
//   R6 186.3 : 2 dispatches, obj folded into 1-block fin (+3.4: obj serialized)
//   R7 208.0 : DIAGNOSTIC noobj x2 -> marginal noobj = 21.7us incl gap
//              => noobj ~= 18us == HBM floor (124.6MB @ 6.9TB/s). Interior done.
// R8: obj as an EXTRA BLOCK of the noobj grid (block NB2) -> runs concurrently
// with the 6084 noobj blocks (latency fully hidden), fin returns to a pure
// L2-hot partial reduce. 2 dispatches, no serial obj penalty.
//
// ws layout (floats):
//  [0..3] obj sums {coor_sq_obj, conf_sq_obj, coor_obj, conf_obj} (block NB2)
//  [16 + 2*blk], [16+2*blk+1] : per-block {coor, conf} noobj partials

#define GHW     52
#define GCELLS  2704          // 52*52
#define NA      9
#define BATCH   256
#define NBLK    (GCELLS * NA) // 24336 elements/sample; NBLK*BATCH = 6,230,016
#define INV52   (1.0f / 52.0f)

#define ELEMS_B 1024                      // elements per block
#define NB2     6084                      // 6,230,016 / 1024 exactly
#define Q4_B    1280                      // float4s per block = 1024*5/4

typedef const __attribute__((address_space(1))) uint32_t glds_g;
typedef __attribute__((address_space(3))) uint32_t glds_l;

__device__ __forceinline__ float sigmoid_exact(float x) {
    return 1.0f / (1.0f + __expf(-x));    // IEEE div; only in the obj block
}

__device__ __forceinline__ float sigmoid_fast(float x) {
    return __builtin_amdgcn_rcpf(1.0f + __expf(-x));  // ~1 ulp; absmax 0.0 R1-R7
}

__device__ __forceinline__ float waveReduceSum(float v) {
#pragma unroll
    for (int o = 32; o > 0; o >>= 1) v += __shfl_down(v, o, 64);
    return v;
}

// ---------------- Kernel 1: noobj blocks [0,NB2) + obj block [NB2] ----------
__global__ __launch_bounds__(256) void yolo_main_kernel(
        const float* __restrict__ pred,
        const float* __restrict__ label,
        const float* __restrict__ anchors,
        float* __restrict__ ws) {
    __shared__ float4 sh4[Q4_B];        // 20KB -> 8 blocks/CU, 32 waves
    __shared__ float anch[18];
    __shared__ float red[4][4];
    int t = threadIdx.x;

    if (blockIdx.x == NB2) {
        // ---------------- obj path: thread t = sample t ----------------
        if (t < 18) anch[t] = anchors[t];
        __syncthreads();

        float4 lab = ((const float4*)label)[t];
        float lx = lab.x, ly = lab.y, lw = lab.z, lh = lab.w;

        int ix = (int)floorf(lx * 52.0f);
        int iy = (int)floorf(ly * 52.0f);
        int idx = ix * GHW + iy;

        // argmax over anchors of squared distance (first-max, strict >)
        int am = 0; float best = -1.0f;
#pragma unroll
        for (int a = 0; a < NA; ++a) {
            float dw = lw - anch[2 * a];
            float dh = lh - anch[2 * a + 1];
            float d = dw * dw + dh * dh;
            if (d > best) { best = d; am = a; }
        }

        const float* p = pred + (((size_t)t * GCELLS + idx) * NA + am) * 5;
        float v0 = p[0], v1 = p[1], v2 = p[2], v3 = p[3], v4 = p[4];

        float aw = anch[2 * am], ah = anch[2 * am + 1];
        float px = (sigmoid_exact(v0) + (float)ix) * INV52;
        float py = (sigmoid_exact(v1) + (float)iy) * INV52;
        float pw = aw * __expf(v2);
        float ph = ah * __expf(v3);
        float pc = sigmoid_exact(v4);

        float agx = ((float)ix + 0.5f) * INV52;
        float agy = ((float)iy + 0.5f) * INV52;

        float d0 = px - agx, d1 = py - agy, d2 = pw - aw, d3 = ph - ah;
        float coor_sq_obj = d0 * d0 + d1 * d1 + d2 * d2 + d3 * d3;
        float conf_sq_obj = pc * pc;

        float e0 = px - lx, e1 = py - ly, e2 = pw - lw, e3 = ph - lh;
        float coor_obj = e0 * e0 + e1 * e1 + e2 * e2 + e3 * e3;

        // IoU (faithful: areas = x2*y2, not (x2-x1)*(y2-y1))
        float lx1 = fmaxf(lx - lw * 0.5f, 0.0f), ly1 = fmaxf(ly - lh * 0.5f, 0.0f);
        float lx2 = fminf(lx + lw * 0.5f, 1.0f), ly2 = fminf(ly + lh * 0.5f, 1.0f);
        float qx1 = fmaxf(px - pw * 0.5f, 0.0f), qy1 = fmaxf(py - ph * 0.5f, 0.0f);
        float qx2 = fminf(px + pw * 0.5f, 1.0f), qy2 = fminf(py + ph * 0.5f, 1.0f);
        float ix1 = fmaxf(lx1, qx1), iy1 = fmaxf(ly1, qy1);
        float ix2 = fminf(lx2, qx2), iy2 = fminf(ly2, qy2);
        float la = lx2 * ly2, pa = qx2 * qy2;
        float inter = fmaxf(ix2 - ix1, 0.0f) * fmaxf(iy2 - iy1, 0.0f);
        float iou = inter / (la + pa - inter);
        float dcf = pc - iou;
        float conf_obj = dcf * dcf;

        float r0 = waveReduceSum(coor_sq_obj);
        float r1 = waveReduceSum(conf_sq_obj);
        float r2 = waveReduceSum(coor_obj);
        float r3 = waveReduceSum(conf_obj);
        int lane = t & 63, wid = t >> 6;
        if (lane == 0) {
            red[0][wid] = r0; red[1][wid] = r1; red[2][wid] = r2; red[3][wid] = r3;
        }
        __syncthreads();
        if (t < 4) {
            ws[t] = red[t][0] + red[t][1] + red[t][2] + red[t][3];
        }
        return;
    }

    // ---------------- noobj path (identical to R6/R7) ----------------
    const float4* __restrict__ g4 = (const float4*)pred;
    size_t f0 = (size_t)blockIdx.x * Q4_B;
    int wbase = t & ~63;                // wave*64, wave-uniform

#pragma unroll
    for (int i = 0; i < 5; ++i) {
        __builtin_amdgcn_global_load_lds(
            (glds_g*)(g4 + f0 + i * 256 + t),
            (glds_l*)(sh4 + i * 256 + wbase),
            16, 0, 0);
    }
    if (t < 18) anch[t] = anchors[t];
    __syncthreads();                    // vmcnt(0) drain

    const float* sh = (const float*)sh4;
    unsigned e0 = (unsigned)blockIdx.x * ELEMS_B + (unsigned)t;
    unsigned a  = e0 % 9u;              // one magic-div per thread
    float accXY = 0.0f, accWH = 0.0f, confAcc = 0.0f;
#pragma unroll
    for (int h = 0; h < 4; ++h) {
        int le = t + h * 256;                       // local element 0..1023
        float aw = anch[2 * a], ah = anch[2 * a + 1];

        const float* m = sh + 5 * le;               // stride-5: 2-way (free)
        float v0 = m[0], v1 = m[1], v2 = m[2], v3 = m[3], v4 = m[4];

        float s0 = sigmoid_fast(v0);
        float s1 = sigmoid_fast(v1);
        float s4 = sigmoid_fast(v4);
        float t0 = s0 - 0.5f;                       // scale by 1/52 deferred
        float t1 = s1 - 0.5f;
        float t2 = aw * (__expf(v2) - 1.0f);        // == pred_w - anchor_w
        float t3 = ah * (__expf(v3) - 1.0f);

        accXY  += t0 * t0 + t1 * t1;
        accWH  += t2 * t2 + t3 * t3;
        confAcc += s4 * s4;

        a += 4u;                                    // (+256) mod 9 == +4
        if (a >= 9u) a -= 9u;
    }
    float coorAcc = accXY * (INV52 * INV52) + accWH;

    float rc = waveReduceSum(coorAcc);
    float rf = waveReduceSum(confAcc);
    int lane = t & 63, wid = t >> 6;
    if (lane == 0) { red[0][wid] = rc; red[1][wid] = rf; }
    __syncthreads();
    if (t == 0) {
        float cs = red[0][0] + red[0][1] + red[0][2] + red[0][3];
        float fs = red[1][0] + red[1][1] + red[1][2] + red[1][3];
        ((float2*)(ws + 16))[blockIdx.x] = make_float2(cs, fs);
    }
}

// ---------------- Kernel 2: partial reduce + final combine ------------------
__global__ __launch_bounds__(256) void yolo_fin_kernel(
        const float* __restrict__ ws,
        float* __restrict__ out) {
    __shared__ float red[2][4];
    int t = threadIdx.x;

    // 6084 float2 slots (48KB, L2-hot), coalesced grid-stride
    const float2* __restrict__ part = (const float2*)(ws + 16);
    float cAcc = 0.0f, fAcc = 0.0f;
    for (int k = t; k < NB2; k += 256) {
        float2 pr = part[k];
        cAcc += pr.x;
        fAcc += pr.y;
    }
    float rc = waveReduceSum(cAcc);
    float rf = waveReduceSum(fAcc);
    int lane = t & 63, wid = t >> 6;
    if (lane == 0) { red[0][wid] = rc; red[1][wid] = rf; }
    __syncthreads();
    if (t == 0) {
        float coor_all = red[0][0] + red[0][1] + red[0][2] + red[0][3];
        float conf_all = red[1][0] + red[1][1] + red[1][2] + red[1][3];
        float coor_l_noobj = (coor_all - ws[0]) / (float)(BATCH * (NBLK - 1) * 4);
        float conf_l_noobj = (conf_all - ws[1]) / (float)(BATCH * (NBLK - 1));
        float coor_l_obj = ws[2] / (float)(BATCH * 4);
        float conf_l_obj = ws[3] / (float)BATCH;
        out[0] = coor_l_obj + coor_l_noobj + conf_l_obj + conf_l_noobj;
    }
}

extern "C" void kernel_launch(void* const* d_in, const int* in_sizes, int n_in,
                              void* d_out, int out_size, void* d_ws, size_t ws_size,
                              hipStream_t stream) {
    const float* pred    = (const float*)d_in[0];
    const float* label   = (const float*)d_in[1];
    const float* anchors = (const float*)d_in[2];
    float* out = (float*)d_out;
    float* ws  = (float*)d_ws;

    yolo_main_kernel<<<NB2 + 1, 256, 0, stream>>>(pred, label, anchors, ws);
    yolo_fin_kernel<<<1, 256, 0, stream>>>(ws, out);
}